// Round 5
// baseline (257.634 us; speedup 1.0000x reference)
//
#include <hip/hip_runtime.h>

#define T_DIM 60
#define LOSS_BLOCKS 1920          // x 512 elems/block = 983040 = NT
#define PARTIALS_OFF 64           // ws floats: [0..59]=npred, [64..]=partials

__global__ void init_kernel(float* __restrict__ ws_npred) {
    int i = threadIdx.x;
    if (i < T_DIM) ws_npred[i] = 0.0f;
}

// n_pred[t] = sum_n mask[n,t]; coalesced grid-stride read, LDS bins.
__global__ void npred_kernel(const float* __restrict__ mask,
                             float* __restrict__ ws_npred, int NT) {
    __shared__ float bins[T_DIM];
    for (int j = threadIdx.x; j < T_DIM; j += blockDim.x) bins[j] = 0.0f;
    __syncthreads();
    int stride = gridDim.x * blockDim.x;
    for (int i = blockIdx.x * blockDim.x + threadIdx.x; i < NT; i += stride) {
        int t = i % T_DIM;
        atomicAdd(&bins[t], mask[i]);
    }
    __syncthreads();
    for (int j = threadIdx.x; j < T_DIM; j += blockDim.x)
        atomicAdd(&ws_npred[j], bins[j]);
}

// One thread per TWO (n,t) elements; ALL loads for both elements are issued
// before any compute. Rounds 1/3/4 proved the limiter is memory-level
// parallelism: compiler allocated 16-32 VGPRs and serialized loads to ~1-2 in
// flight/wave -> ~2.7 TB/s effective (latency-bound), regardless of
// coalescing pattern. (256,1) launch bounds + ~24 live float4s forces the
// register allocator to keep ~28 loads outstanding per wave.
__device__ __forceinline__ float elem_loss(float2 xv, float mk, float npr,
                                           const float4* mu4, const float4* sg4,
                                           float4 p0, float4 p1) {
    const float LOG_2PI = 1.8378770664093453f;
    float4 mv0 = mu4[0], mv1 = mu4[1], mv2 = mu4[2], mv3 = mu4[3];
    float4 sg0 = sg4[0], sg1 = sg4[1], sg2 = sg4[2], sg3 = sg4[3];
    float4 sg4v = sg4[4], sg5 = sg4[5], sg6 = sg4[6], sg7 = sg4[7];

    float mus[16] = {mv0.x, mv0.y, mv0.z, mv0.w, mv1.x, mv1.y, mv1.z, mv1.w,
                     mv2.x, mv2.y, mv2.z, mv2.w, mv3.x, mv3.y, mv3.z, mv3.w};
    float4 sg[8] = {sg0, sg1, sg2, sg3, sg4v, sg5, sg6, sg7};
    float pis[8] = {p0.x, p0.y, p0.z, p0.w, p1.x, p1.y, p1.z, p1.w};

    float lp[8];
#pragma unroll
    for (int m = 0; m < 8; ++m) {
        float a = sg[m].x, b = sg[m].y, c = sg[m].w;
        float d1 = xv.x - mus[2 * m];
        float d2 = xv.y - mus[2 * m + 1];
        float det = a * c - b * b;          // SPD: det >= 0.25
        float maha = (c * d1 * d1 - 2.0f * b * d1 * d2 + a * d2 * d2) / det;
        lp[m] = pis[m] - LOG_2PI - 0.5f * (maha + __logf(det));
    }
    float mx = lp[0];
#pragma unroll
    for (int m = 1; m < 8; ++m) mx = fmaxf(mx, lp[m]);
    float s = 0.0f;
#pragma unroll
    for (int m = 0; m < 8; ++m) s += __expf(lp[m] - mx);
    float lse_num = mx + __logf(s);

    float pmx = pis[0];
#pragma unroll
    for (int m = 1; m < 8; ++m) pmx = fmaxf(pmx, pis[m]);
    float ps = 0.0f;
#pragma unroll
    for (int m = 0; m < 8; ++m) ps += __expf(pis[m] - pmx);
    float lse_pi = pmx + __logf(ps);

    return (lse_pi - lse_num) * mk / npr;   // = -gmm_lp, masked & scaled
}

__global__ __launch_bounds__(256, 1)
void loss_kernel(const float* __restrict__ mu,
                 const float* __restrict__ sigma,
                 const float* __restrict__ pi,
                 const float* __restrict__ x,
                 const float* __restrict__ mask,
                 const float* __restrict__ ws_npred,
                 float* __restrict__ ws_partials, int NT) {
    int tid = threadIdx.x;
    int i0 = blockIdx.x * 512 + tid;        // element A
    int i1 = i0 + 256;                      // element B (still coalesced)
    float acc = 0.0f;

    if (i1 < NT) {                          // both valid (always true here)
        int n0 = i0 / T_DIM, t0 = i0 - n0 * T_DIM;
        int n1 = i1 / T_DIM, t1 = i1 - n1 * T_DIM;

        // ---- issue EVERYTHING first (28 independent loads) ----
        const float4* mu4a = (const float4*)(mu + (size_t)i0 * 16);
        const float4* sg4a = (const float4*)(sigma + (size_t)i0 * 32);
        const float4* mu4b = (const float4*)(mu + (size_t)i1 * 16);
        const float4* sg4b = (const float4*)(sigma + (size_t)i1 * 32);
        float2 xva = ((const float2*)x)[i0];
        float2 xvb = ((const float2*)x)[i1];
        float mka = mask[i0];
        float mkb = mask[i1];
        float npra = ws_npred[t0];
        float nprb = ws_npred[t1];
        const float4* pia = (const float4*)(pi + (size_t)n0 * 8);
        const float4* pib = (const float4*)(pi + (size_t)n1 * 8);
        float4 pa0 = pia[0], pa1 = pia[1];
        float4 pb0 = pib[0], pb1 = pib[1];

        acc  = elem_loss(xva, mka, npra, mu4a, sg4a, pa0, pa1);
        acc += elem_loss(xvb, mkb, nprb, mu4b, sg4b, pb0, pb1);
    } else if (i0 < NT) {
        int n0 = i0 / T_DIM, t0 = i0 - n0 * T_DIM;
        const float4* pia = (const float4*)(pi + (size_t)n0 * 8);
        acc = elem_loss(((const float2*)x)[i0], mask[i0], ws_npred[t0],
                        (const float4*)(mu + (size_t)i0 * 16),
                        (const float4*)(sigma + (size_t)i0 * 32),
                        pia[0], pia[1]);
    }

    // wave (64) shuffle reduce -> LDS -> one plain store per block
#pragma unroll
    for (int off = 32; off > 0; off >>= 1)
        acc += __shfl_down(acc, off);
    __shared__ float wsum[4];
    int lane = tid & 63;
    int wid = tid >> 6;
    if (lane == 0) wsum[wid] = acc;
    __syncthreads();
    if (tid == 0)
        ws_partials[blockIdx.x] = wsum[0] + wsum[1] + wsum[2] + wsum[3];
}

// Single block sums the block partials into out[0].
__global__ void finalize_kernel(const float* __restrict__ ws_partials,
                                float* __restrict__ out, int nblocks) {
    float s = 0.0f;
    for (int i = threadIdx.x; i < nblocks; i += blockDim.x)
        s += ws_partials[i];
#pragma unroll
    for (int off = 32; off > 0; off >>= 1)
        s += __shfl_down(s, off);
    __shared__ float wsum[4];
    int lane = threadIdx.x & 63;
    int wid = threadIdx.x >> 6;
    if (lane == 0) wsum[wid] = s;
    __syncthreads();
    if (threadIdx.x == 0)
        out[0] = wsum[0] + wsum[1] + wsum[2] + wsum[3];
}

extern "C" void kernel_launch(void* const* d_in, const int* in_sizes, int n_in,
                              void* d_out, int out_size, void* d_ws, size_t ws_size,
                              hipStream_t stream) {
    const float* mu    = (const float*)d_in[0];   // (N,T,M,K)
    const float* sigma = (const float*)d_in[1];   // (N,T,M,K,K)
    const float* pi    = (const float*)d_in[2];   // (N,M)
    const float* x     = (const float*)d_in[3];   // (N,T,K)
    const float* mask  = (const float*)d_in[4];   // (N,T)
    float* out = (float*)d_out;
    float* ws_npred    = (float*)d_ws;                 // 60 floats
    float* ws_partials = (float*)d_ws + PARTIALS_OFF;  // 1920 floats

    int NT = in_sizes[4];                          // N*T = 983040

    hipLaunchKernelGGL(init_kernel, dim3(1), dim3(64), 0, stream, ws_npred);
    hipLaunchKernelGGL(npred_kernel, dim3(240), dim3(256), 0, stream,
                       mask, ws_npred, NT);
    hipLaunchKernelGGL(loss_kernel, dim3(LOSS_BLOCKS), dim3(256), 0, stream,
                       mu, sigma, pi, x, mask, ws_npred, ws_partials, NT);
    hipLaunchKernelGGL(finalize_kernel, dim3(1), dim3(256), 0, stream,
                       ws_partials, out, LOSS_BLOCKS);
}

// Round 6
// 250.324 us; speedup vs baseline: 1.0292x; 1.0292x over previous
//
#include <hip/hip_runtime.h>

#define T_DIM 60
#define LOSS_BLOCKS 3840          // 3840*256 threads = 983040 = NT lanes; 8 lanes/elem, 8 iters
#define ITERS 8
#define PARTIALS_OFF 64           // ws floats: [0..59]=npred, [64..]=partials

__global__ void init_kernel(float* __restrict__ ws_npred) {
    int i = threadIdx.x;
    if (i < T_DIM) ws_npred[i] = 0.0f;
}

// n_pred[t] = sum_n mask[n,t]; coalesced grid-stride read, LDS bins.
__global__ void npred_kernel(const float* __restrict__ mask,
                             float* __restrict__ ws_npred, int NT) {
    __shared__ float bins[T_DIM];
    for (int j = threadIdx.x; j < T_DIM; j += blockDim.x) bins[j] = 0.0f;
    __syncthreads();
    int stride = gridDim.x * blockDim.x;
    for (int i = blockIdx.x * blockDim.x + threadIdx.x; i < NT; i += stride) {
        int t = i % T_DIM;
        atomicAdd(&bins[t], mask[i]);
    }
    __syncthreads();
    for (int j = threadIdx.x; j < T_DIM; j += blockDim.x)
        atomicAdd(&ws_npred[j], bins[j]);
}

// Oct-cooperative, copy-clone access pattern: 8 lanes per (n,t) element; lane l
// owns mixture component l = exactly ONE float4 of sigma and ONE float2 of mu.
// Per wave-instruction the 64 lanes read 64 CONSECUTIVE float4s/float2s and use
// each value once — structurally identical to the 6.29 TB/s copy ubench (m13).
// Rounds 1-5 (deep per-lane grain, 192B/elem/lane) all pinned at ~2.7 TB/s
// effective regardless of coalescing/VGPR/atomic changes; this tests (and, if
// the theory holds, fixes) the load-use-depth + occupancy limiter.
// LSE over the 8 components = 3 __shfl_xor steps (lanes stay inside the oct).
__global__ __launch_bounds__(256)
void loss_kernel(const float* __restrict__ mu,
                 const float* __restrict__ sigma,
                 const float* __restrict__ pi,
                 const float* __restrict__ x,
                 const float* __restrict__ mask,
                 const float* __restrict__ ws_npred,
                 float* __restrict__ ws_partials, int NT) {
    const float LOG_2PI = 1.8378770664093453f;
    const int OCTS = NT / 8;                 // 122880 octs, each does ITERS elems
    int tid = threadIdx.x;
    int g = blockIdx.x * 256 + tid;
    int l = g & 7;                           // component owned by this lane
    int oct = g >> 3;                        // global oct id (0..OCTS-1)
    float acc = 0.0f;

#pragma unroll
    for (int it = 0; it < ITERS; ++it) {
        int e = it * OCTS + oct;             // element (n*T + t)
        int n = e / T_DIM;
        int t = e - n * T_DIM;

        // copy-pattern loads: lane -> consecutive float4/float2 indices
        float4 sg = ((const float4*)sigma)[(size_t)e * 8 + l];  // 2x2 cov block
        float2 m2 = ((const float2*)mu)[(size_t)e * 8 + l];     // component mean
        float2 xv = ((const float2*)x)[e];                      // 8-lane broadcast
        float p   = pi[(size_t)n * 8 + l];                      // logit (L1-hot)
        float mk  = mask[e];
        float npr = ws_npred[t];

        // closed-form 2x2: det = ac-b^2, maha = (c d1^2 - 2b d1 d2 + a d2^2)/det
        float a = sg.x, b = sg.y, c = sg.w;
        float d1 = xv.x - m2.x, d2 = xv.y - m2.y;
        float det = a * c - b * b;           // SPD: det >= 0.25
        float maha = (c * d1 * d1 - 2.0f * b * d1 * d2 + a * d2 * d2) / det;
        float lp = p - LOG_2PI - 0.5f * (maha + __logf(det));

        // LSE over the 8 components (within the oct)
        float mx = lp;
        mx = fmaxf(mx, __shfl_xor(mx, 1));
        mx = fmaxf(mx, __shfl_xor(mx, 2));
        mx = fmaxf(mx, __shfl_xor(mx, 4));
        float s = __expf(lp - mx);
        s += __shfl_xor(s, 1);
        s += __shfl_xor(s, 2);
        s += __shfl_xor(s, 4);
        float lse_num = mx + __logf(s);

        // LSE over pi logits (categorical normalizer)
        float pmx = p;
        pmx = fmaxf(pmx, __shfl_xor(pmx, 1));
        pmx = fmaxf(pmx, __shfl_xor(pmx, 2));
        pmx = fmaxf(pmx, __shfl_xor(pmx, 4));
        float ps = __expf(p - pmx);
        ps += __shfl_xor(ps, 1);
        ps += __shfl_xor(ps, 2);
        ps += __shfl_xor(ps, 4);
        float lse_pi = pmx + __logf(ps);

        if (l == 0)
            acc += (lse_pi - lse_num) * mk / npr;   // -gmm_lp, masked & scaled
    }

    // wave (64) shuffle reduce -> LDS -> one plain store per block
#pragma unroll
    for (int off = 32; off > 0; off >>= 1)
        acc += __shfl_down(acc, off);
    __shared__ float wsum[4];
    int lane = tid & 63;
    int wid = tid >> 6;
    if (lane == 0) wsum[wid] = acc;
    __syncthreads();
    if (tid == 0)
        ws_partials[blockIdx.x] = wsum[0] + wsum[1] + wsum[2] + wsum[3];
}

// Single block sums the block partials into out[0].
__global__ void finalize_kernel(const float* __restrict__ ws_partials,
                                float* __restrict__ out, int nblocks) {
    float s = 0.0f;
    for (int i = threadIdx.x; i < nblocks; i += blockDim.x)
        s += ws_partials[i];
#pragma unroll
    for (int off = 32; off > 0; off >>= 1)
        s += __shfl_down(s, off);
    __shared__ float wsum[4];
    int lane = threadIdx.x & 63;
    int wid = threadIdx.x >> 6;
    if (lane == 0) wsum[wid] = s;
    __syncthreads();
    if (threadIdx.x == 0)
        out[0] = wsum[0] + wsum[1] + wsum[2] + wsum[3];
}

extern "C" void kernel_launch(void* const* d_in, const int* in_sizes, int n_in,
                              void* d_out, int out_size, void* d_ws, size_t ws_size,
                              hipStream_t stream) {
    const float* mu    = (const float*)d_in[0];   // (N,T,M,K)
    const float* sigma = (const float*)d_in[1];   // (N,T,M,K,K)
    const float* pi    = (const float*)d_in[2];   // (N,M)
    const float* x     = (const float*)d_in[3];   // (N,T,K)
    const float* mask  = (const float*)d_in[4];   // (N,T)
    float* out = (float*)d_out;
    float* ws_npred    = (float*)d_ws;                 // 60 floats
    float* ws_partials = (float*)d_ws + PARTIALS_OFF;  // 3840 floats

    int NT = in_sizes[4];                          // N*T = 983040

    hipLaunchKernelGGL(init_kernel, dim3(1), dim3(64), 0, stream, ws_npred);
    hipLaunchKernelGGL(npred_kernel, dim3(240), dim3(256), 0, stream,
                       mask, ws_npred, NT);
    hipLaunchKernelGGL(loss_kernel, dim3(LOSS_BLOCKS), dim3(256), 0, stream,
                       mu, sigma, pi, x, mask, ws_npred, ws_partials, NT);
    hipLaunchKernelGGL(finalize_kernel, dim3(1), dim3(256), 0, stream,
                       ws_partials, out, LOSS_BLOCKS);
}